// Round 5
// baseline (1193.501 us; speedup 1.0000x reference)
//
#include <hip/hip_runtime.h>

#define B_  16
#define S_  128
#define N_  13
#define D_  128
#define E_  6
#define M_  64
#define H_  4
#define HD_ 16

// compiler-only ordering for same-wave LDS park->read (DS pipe is in-order per wave;
// cross-wave reads here are dummy row-0 values whose results are discarded)
#define LDS_ORDER() __asm__ __volatile__("" ::: "memory")

// A&S 7.1.26 erf approximation, |eps| < 1.5e-7 (well under tolerance budget)
__device__ __forceinline__ float erf_fast(float x) {
    float ax = fabsf(x);
    float t  = __builtin_amdgcn_rcpf(fmaf(0.3275911f, ax, 1.0f));
    float p  = t * fmaf(t, fmaf(t, fmaf(t, fmaf(t, 1.061405429f, -1.453152027f),
                                        1.421413741f), -0.284496736f), 0.254829592f);
    float r  = fmaf(-p, __expf(-ax * ax), 1.0f);
    return copysignf(r, x);
}
__device__ __forceinline__ float geluf(float x) {
    return 0.5f * x * (1.0f + erf_fast(x * 0.7071067811865475f));
}
__device__ __forceinline__ float sigm(float x) { return 1.0f / (1.0f + __expf(-x)); }
__device__ __forceinline__ float wsum64(float v) {
#pragma unroll
    for (int o = 32; o; o >>= 1) v += __shfl_xor(v, o, 64);
    return v;
}
// 4 independent wave reductions, scalar refs (NO arrays -> stays in VGPRs)
__device__ __forceinline__ void wsum4s(float &a, float &b, float &c, float &d) {
#pragma unroll
    for (int o = 32; o; o >>= 1) {
        float ta = __shfl_xor(a, o, 64);
        float tb = __shfl_xor(b, o, 64);
        float tc = __shfl_xor(c, o, 64);
        float td = __shfl_xor(d, o, 64);
        a += ta; b += tb; c += tc; d += td;
    }
}
template <bool DOGELU>
__device__ __forceinline__ void ln4s(float &a, float &b, float &c, float &d,
                                     float lg, float lb) {
    float ma = a, mb = b, mc = c, md = d;
    wsum4s(ma, mb, mc, md);
    float da = a - ma * (1.f / 64.f);
    float db = b - mb * (1.f / 64.f);
    float dc = c - mc * (1.f / 64.f);
    float dd = d - md * (1.f / 64.f);
    float sa = da * da, sb = db * db, sc2 = dc * dc, sd = dd * dd;
    wsum4s(sa, sb, sc2, sd);
    a = da * rsqrtf(sa * (1.f / 64.f) + 1e-5f) * lg + lb;
    b = db * rsqrtf(sb * (1.f / 64.f) + 1e-5f) * lg + lb;
    c = dc * rsqrtf(sc2 * (1.f / 64.f) + 1e-5f) * lg + lb;
    d = dd * rsqrtf(sd * (1.f / 64.f) + 1e-5f) * lg + lb;
    if (DOGELU) { a = geluf(a); b = geluf(b); c = geluf(c); d = geluf(d); }
}

struct Params {
    const float *node_states, *edge_features;
    const float *ee_w1, *ee_b1, *ee_ln_g, *ee_ln_b, *ee_w2, *ee_b2;
    const float *ts_w1, *ts_b1, *ts_ln_g, *ts_ln_b, *ts_w2, *ts_b2, *ts_w3, *ts_b3;
    const float *mc_w1, *mc_b1, *mc_ln_g, *mc_ln_b, *mc_w2, *mc_b2;
    const float *at_in_w, *at_in_b, *at_out_w, *at_out_b;
    const float *ag_w1, *ag_b1, *ag_ln_g, *ag_ln_b, *ag_w2, *ag_b2;
    const float *gt_w, *gt_b, *nn_ln_g, *nn_ln_b, *mn_ln_g, *mn_ln_b;
    float *out;
};

// 4-edge-per-wave GEMV step: x0..x3 are float4 chunks (one per edge),
// w0..w3 the 4 weight rows for this lane's output channel.
#define DOT4X4(A0, A1, A2, A3)                              \
    A0 += x0.x * w0 + x0.y * w1 + x0.z * w2 + x0.w * w3;    \
    A1 += x1.x * w0 + x1.y * w1 + x1.z * w2 + x1.w * w3;    \
    A2 += x2.x * w0 + x2.y * w1 + x2.z * w2 + x2.w * w3;    \
    A3 += x3.x * w0 + x3.y * w1 + x3.z * w2 + x3.w * w3;

// one block per (b,s,target). 4 waves; wave w owns edges {w, w+4, w+8, (w==0: 12)},
// batched 4-wide inside each GEMV stage; inter-stage vectors parked in LDS.
// lane = M-channel. launch_bounds(256,6): 6 blocks/CU (LDS 6x25.5KB=153KB fits).
__global__ __launch_bounds__(256, 6) void petri_kernel(Params p) {
    const int tid  = threadIdx.x;
    const int wave = tid >> 6;
    const int lane = tid & 63;
    const int blk  = blockIdx.x;       // 0 .. B*S*N-1
    const int bs   = blk / N_;         // b*S + s
    const int t    = blk - bs * N_;    // target node

    const int  j0 = wave, j1 = wave + 4, j2 = wave + 8;
    const bool act3 = (wave == 0);
    const int  j3 = act3 ? 12 : 0;     // inactive -> alias row 0, results discarded

    __shared__ float ns[N_][D_];        // node states of this (b,s)
    __shared__ float xbuf[N_][M_];      // per-edge parking: t1 -> mh -> wm
    __shared__ float encb[N_][8];       // encoded edge features (6 used)
    __shared__ float qkv[N_][3 * M_];   // per source edge
    __shared__ float sc[H_][N_][N_];    // scores / attn
    __shared__ float wsm[H_][16];       // per-head column sums of attn
    __shared__ float aggp[M_];
    __shared__ float agg2[M_];
    __shared__ float a1l[D_];
    __shared__ float nil[D_];
    __shared__ float gzp[2][D_];
    __shared__ float red[4];

    // ---- stage node states -> LDS ----
    {
        const float *g = p.node_states + (size_t)bs * N_ * D_;
        for (int i = tid; i < N_ * D_ / 4; i += 256)
            ((float4 *)ns)[i] = ((const float4 *)g)[i];
    }
    __syncthreads();

    // =======================  edge phase  =======================
    float acc0, acc1, acc2, acc3;

    // ---- E1: edge features @ ee_w1 -> LN -> gelu ----
    {
        const float *efb = p.edge_features + ((size_t)bs * N_ * N_ + t) * E_;
        const float *e0p = efb + j0 * (N_ * E_);
        const float *e1p = efb + j1 * (N_ * E_);
        const float *e2p = efb + j2 * (N_ * E_);
        const float *e3p = efb + j3 * (N_ * E_);
        float2 f0a = ((const float2 *)e0p)[0], f0b = ((const float2 *)e0p)[1], f0c = ((const float2 *)e0p)[2];
        float2 f1a = ((const float2 *)e1p)[0], f1b = ((const float2 *)e1p)[1], f1c = ((const float2 *)e1p)[2];
        float2 f2a = ((const float2 *)e2p)[0], f2b = ((const float2 *)e2p)[1], f2c = ((const float2 *)e2p)[2];
        float2 f3a = ((const float2 *)e3p)[0], f3b = ((const float2 *)e3p)[1], f3c = ((const float2 *)e3p)[2];
        float bb = p.ee_b1[lane];
        acc0 = acc1 = acc2 = acc3 = bb;
        { float w = p.ee_w1[0 * M_ + lane]; acc0 += f0a.x * w; acc1 += f1a.x * w; acc2 += f2a.x * w; acc3 += f3a.x * w; }
        { float w = p.ee_w1[1 * M_ + lane]; acc0 += f0a.y * w; acc1 += f1a.y * w; acc2 += f2a.y * w; acc3 += f3a.y * w; }
        { float w = p.ee_w1[2 * M_ + lane]; acc0 += f0b.x * w; acc1 += f1b.x * w; acc2 += f2b.x * w; acc3 += f3b.x * w; }
        { float w = p.ee_w1[3 * M_ + lane]; acc0 += f0b.y * w; acc1 += f1b.y * w; acc2 += f2b.y * w; acc3 += f3b.y * w; }
        { float w = p.ee_w1[4 * M_ + lane]; acc0 += f0c.x * w; acc1 += f1c.x * w; acc2 += f2c.x * w; acc3 += f3c.x * w; }
        { float w = p.ee_w1[5 * M_ + lane]; acc0 += f0c.y * w; acc1 += f1c.y * w; acc2 += f2c.y * w; acc3 += f3c.y * w; }
    }
    ln4s<true>(acc0, acc1, acc2, acc3, p.ee_ln_g[lane], p.ee_ln_b[lane]);

    // ---- E2: project back to E, park in encb ----
#pragma unroll
    for (int e = 0; e < E_; e++) {
        float w = p.ee_w2[lane * E_ + e];
        float r0 = acc0 * w, r1 = acc1 * w, r2 = acc2 * w, r3 = acc3 * w;
        wsum4s(r0, r1, r2, r3);
        if (lane == e) {
            float be = p.ee_b2[e];
            encb[j0][e] = r0 + be;
            encb[j1][e] = r1 + be;
            encb[j2][e] = r2 + be;
            if (act3) encb[j3][e] = r3 + be;
        }
    }
    LDS_ORDER();

    // broadcast-load enc vectors (per-edge) into registers
    float4 enA0 = *(const float4 *)&encb[j0][0]; float2 enB0 = *(const float2 *)&encb[j0][4];
    float4 enA1 = *(const float4 *)&encb[j1][0]; float2 enB1 = *(const float2 *)&encb[j1][4];
    float4 enA2 = *(const float4 *)&encb[j2][0]; float2 enB2 = *(const float2 *)&encb[j2][4];
    float4 enA3 = *(const float4 *)&encb[j3][0]; float2 enB3 = *(const float2 *)&encb[j3][4];

    // ---- TS: transition strength E -> M -> 32 -> 1 ----
    float ts0, ts1, ts2, ts3;
    {
        float t10, t11, t12, t13;
        float bb = p.ts_b1[lane];
        t10 = t11 = t12 = t13 = bb;
        { float w = p.ts_w1[0 * M_ + lane]; t10 += enA0.x * w; t11 += enA1.x * w; t12 += enA2.x * w; t13 += enA3.x * w; }
        { float w = p.ts_w1[1 * M_ + lane]; t10 += enA0.y * w; t11 += enA1.y * w; t12 += enA2.y * w; t13 += enA3.y * w; }
        { float w = p.ts_w1[2 * M_ + lane]; t10 += enA0.z * w; t11 += enA1.z * w; t12 += enA2.z * w; t13 += enA3.z * w; }
        { float w = p.ts_w1[3 * M_ + lane]; t10 += enA0.w * w; t11 += enA1.w * w; t12 += enA2.w * w; t13 += enA3.w * w; }
        { float w = p.ts_w1[4 * M_ + lane]; t10 += enB0.x * w; t11 += enB1.x * w; t12 += enB2.x * w; t13 += enB3.x * w; }
        { float w = p.ts_w1[5 * M_ + lane]; t10 += enB0.y * w; t11 += enB1.y * w; t12 += enB2.y * w; t13 += enB3.y * w; }
        ln4s<true>(t10, t11, t12, t13, p.ts_ln_g[lane], p.ts_ln_b[lane]);
        xbuf[j0][lane] = t10;
        xbuf[j1][lane] = t11;
        xbuf[j2][lane] = t12;
        if (act3) xbuf[j3][lane] = t13;
        LDS_ORDER();

        const int l31 = lane & 31;
        float b2v = p.ts_b2[l31];
        float t20 = b2v, t21 = b2v, t22 = b2v, t23 = b2v;
#pragma unroll 4
        for (int m4 = 0; m4 < M_ / 4; m4++) {
            float4 x0 = *(const float4 *)&xbuf[j0][4 * m4];
            float4 x1 = *(const float4 *)&xbuf[j1][4 * m4];
            float4 x2 = *(const float4 *)&xbuf[j2][4 * m4];
            float4 x3 = *(const float4 *)&xbuf[j3][4 * m4];
            const float *wr = p.ts_w2 + (4 * m4) * 32 + l31;
            float w0 = wr[0], w1 = wr[32], w2 = wr[64], w3 = wr[96];
            DOT4X4(t20, t21, t22, t23)
        }
        float w3v = p.ts_w3[l31], b3v = p.ts_b3[0];
        float r0 = geluf(t20) * w3v, r1 = geluf(t21) * w3v;
        float r2 = geluf(t22) * w3v, r3 = geluf(t23) * w3v;
        wsum4s(r0, r1, r2, r3);  // 32-halves duplicated -> x0.5
        ts0 = sigm(r0 * 0.5f + b3v);
        ts1 = sigm(r1 * 0.5f + b3v);
        ts2 = sigm(r2 * 0.5f + b3v);
        ts3 = sigm(r3 * 0.5f + b3v);
    }

    // ---- MC1: concat(src_state, enc) @ mc_w1 -> LN -> gelu, park mh ----
    {
        float bb = p.mc_b1[lane];
        acc0 = acc1 = acc2 = acc3 = bb;
#pragma unroll 4
        for (int d4 = 0; d4 < D_ / 4; d4++) {
            float4 x0 = *(const float4 *)&ns[j0][4 * d4];
            float4 x1 = *(const float4 *)&ns[j1][4 * d4];
            float4 x2 = *(const float4 *)&ns[j2][4 * d4];
            float4 x3 = *(const float4 *)&ns[j3][4 * d4];
            const float *wr = p.mc_w1 + (size_t)(4 * d4) * M_ + lane;
            float w0 = wr[0], w1 = wr[M_], w2 = wr[2 * M_], w3 = wr[3 * M_];
            DOT4X4(acc0, acc1, acc2, acc3)
        }
        { float w = p.mc_w1[(D_ + 0) * M_ + lane]; acc0 += enA0.x * w; acc1 += enA1.x * w; acc2 += enA2.x * w; acc3 += enA3.x * w; }
        { float w = p.mc_w1[(D_ + 1) * M_ + lane]; acc0 += enA0.y * w; acc1 += enA1.y * w; acc2 += enA2.y * w; acc3 += enA3.y * w; }
        { float w = p.mc_w1[(D_ + 2) * M_ + lane]; acc0 += enA0.z * w; acc1 += enA1.z * w; acc2 += enA2.z * w; acc3 += enA3.z * w; }
        { float w = p.mc_w1[(D_ + 3) * M_ + lane]; acc0 += enA0.w * w; acc1 += enA1.w * w; acc2 += enA2.w * w; acc3 += enA3.w * w; }
        { float w = p.mc_w1[(D_ + 4) * M_ + lane]; acc0 += enB0.x * w; acc1 += enB1.x * w; acc2 += enB2.x * w; acc3 += enB3.x * w; }
        { float w = p.mc_w1[(D_ + 5) * M_ + lane]; acc0 += enB0.y * w; acc1 += enB1.y * w; acc2 += enB2.y * w; acc3 += enB3.y * w; }
        ln4s<true>(acc0, acc1, acc2, acc3, p.mc_ln_g[lane], p.mc_ln_b[lane]);
        xbuf[j0][lane] = acc0;
        xbuf[j1][lane] = acc1;
        xbuf[j2][lane] = acc2;
        if (act3) xbuf[j3][lane] = acc3;   // mh (t1 consumed)
        LDS_ORDER();
    }

    // ---- MC2: mh @ mc_w2 ; wm = LN(msg*ts), park wm ----
    {
        float bb = p.mc_b2[lane];
        float m0 = bb, m1 = bb, m2 = bb, m3 = bb;
#pragma unroll 4
        for (int k4 = 0; k4 < M_ / 4; k4++) {
            float4 x0 = *(const float4 *)&xbuf[j0][4 * k4];
            float4 x1 = *(const float4 *)&xbuf[j1][4 * k4];
            float4 x2 = *(const float4 *)&xbuf[j2][4 * k4];
            float4 x3 = *(const float4 *)&xbuf[j3][4 * k4];
            const float *wr = p.mc_w2 + (size_t)(4 * k4) * M_ + lane;
            float w0 = wr[0], w1 = wr[M_], w2 = wr[2 * M_], w3 = wr[3 * M_];
            DOT4X4(m0, m1, m2, m3)
        }
        m0 *= ts0; m1 *= ts1; m2 *= ts2; m3 *= ts3;
        ln4s<false>(m0, m1, m2, m3, p.mn_ln_g[lane], p.mn_ln_b[lane]);
        xbuf[j0][lane] = m0;
        xbuf[j1][lane] = m1;
        xbuf[j2][lane] = m2;
        if (act3) xbuf[j3][lane] = m3;     // wm (mh consumed)
        LDS_ORDER();
    }

    // ---- AT: qkv = wm @ at_in_w + b ----
    {
        float qb = p.at_in_b[lane];
        float kb = p.at_in_b[M_ + lane];
        float vb = p.at_in_b[2 * M_ + lane];
        float qa0 = qb, qa1 = qb, qa2 = qb, qa3 = qb;
        float ka0 = kb, ka1 = kb, ka2 = kb, ka3 = kb;
        float va0 = vb, va1 = vb, va2 = vb, va3 = vb;
#define AT_STEP(COMP, WR)                                                  \
        { float wq = (WR)[lane], wk = (WR)[M_ + lane], wv = (WR)[2 * M_ + lane]; \
          qa0 += x0.COMP * wq; ka0 += x0.COMP * wk; va0 += x0.COMP * wv;   \
          qa1 += x1.COMP * wq; ka1 += x1.COMP * wk; va1 += x1.COMP * wv;   \
          qa2 += x2.COMP * wq; ka2 += x2.COMP * wk; va2 += x2.COMP * wv;   \
          qa3 += x3.COMP * wq; ka3 += x3.COMP * wk; va3 += x3.COMP * wv; }
#pragma unroll 2
        for (int k4 = 0; k4 < M_ / 4; k4++) {
            float4 x0 = *(const float4 *)&xbuf[j0][4 * k4];
            float4 x1 = *(const float4 *)&xbuf[j1][4 * k4];
            float4 x2 = *(const float4 *)&xbuf[j2][4 * k4];
            float4 x3 = *(const float4 *)&xbuf[j3][4 * k4];
            const float *wr = p.at_in_w + (size_t)(4 * k4) * 3 * M_;
            AT_STEP(x, wr)
            AT_STEP(y, wr + 3 * M_)
            AT_STEP(z, wr + 6 * M_)
            AT_STEP(w, wr + 9 * M_)
        }
#undef AT_STEP
        qkv[j0][lane] = qa0; qkv[j0][M_ + lane] = ka0; qkv[j0][2 * M_ + lane] = va0;
        qkv[j1][lane] = qa1; qkv[j1][M_ + lane] = ka1; qkv[j1][2 * M_ + lane] = va1;
        qkv[j2][lane] = qa2; qkv[j2][M_ + lane] = ka2; qkv[j2][2 * M_ + lane] = va2;
        if (act3) {
            qkv[j3][lane] = qa3; qkv[j3][M_ + lane] = ka3; qkv[j3][2 * M_ + lane] = va3;
        }
    }
    __syncthreads();

    // =======================  attention phase  =======================
    for (int pidx = tid; pidx < H_ * N_ * N_; pidx += 256) {
        int hh = pidx / (N_ * N_), r = pidx % (N_ * N_);
        int q = r / N_, k = r % N_;
        float s = 0.f;
#pragma unroll
        for (int d = 0; d < HD_; d++)
            s += qkv[q][hh * HD_ + d] * qkv[k][M_ + hh * HD_ + d];
        sc[hh][q][k] = s * 0.25f;  // 1/sqrt(16)
    }
    __syncthreads();
    if (tid < H_ * N_) {  // softmax rows
        int hh = tid / N_, q = tid % N_;
        float mx = -1e30f;
        for (int k = 0; k < N_; k++) mx = fmaxf(mx, sc[hh][q][k]);
        float se = 0.f;
        for (int k = 0; k < N_; k++) {
            float e = __expf(sc[hh][q][k] - mx);
            se += e; sc[hh][q][k] = e;
        }
        float inv = 1.f / se;
        for (int k = 0; k < N_; k++) sc[hh][q][k] *= inv;
    }
    __syncthreads();
    if (tid < H_ * N_) {  // column sums over q (mean-over-q is linear)
        int hh = tid / N_, k = tid % N_;
        float s = 0.f;
        for (int q = 0; q < N_; q++) s += sc[hh][q][k];
        wsm[hh][k] = s;
    }
    __syncthreads();
    if (tid < M_) {  // agg_pre = (1/13) * (colsum @ v)
        int hh  = tid >> 4;
        float s = 0.f;
        for (int k = 0; k < N_; k++) s += wsm[hh][k] * qkv[k][2 * M_ + tid];
        aggp[tid] = s * (1.0f / 13.0f);
    }
    __syncthreads();
    if (tid < M_) {  // at_out (after mean, by linearity)
        float s = p.at_out_b[tid];
        for (int k = 0; k < M_; k++) s += aggp[k] * p.at_out_w[k * M_ + tid];
        agg2[tid] = s;
    }
    __syncthreads();

    // =======================  node update phase  =======================
    float a1 = 0.f;
    if (tid < D_) {
        a1 = p.ag_b1[tid];
        for (int k = 0; k < M_; k++) a1 += agg2[k] * p.ag_w1[k * D_ + tid];
    }
    {   // LN over 128 (threads 0..127 = waves 0,1)
        float s = wsum64(tid < D_ ? a1 : 0.f);
        if (lane == 0) red[wave] = s;
        __syncthreads();
        float mean = (red[0] + red[1]) * (1.f / 128.f);
        __syncthreads();
        float d  = a1 - mean;
        float s2 = wsum64(tid < D_ ? d * d : 0.f);
        if (lane == 0) red[wave] = s2;
        __syncthreads();
        float var = (red[0] + red[1]) * (1.f / 128.f);
        __syncthreads();
        if (tid < D_)
            a1 = geluf(d * rsqrtf(var + 1e-5f) * p.ag_ln_g[tid] + p.ag_ln_b[tid]);
    }
    if (tid < D_) a1l[tid] = a1;
    __syncthreads();
    float niv = 0.f;
    if (tid < D_) {
        niv = p.ag_b2[tid];
        for (int k = 0; k < D_; k++) niv += a1l[k] * p.ag_w2[k * D_ + tid];
        nil[tid] = niv;
    }
    __syncthreads();
    {   // gate GEMV split across all 4 waves: half 0 -> node part, half 1 -> ni part
        int half = tid >> 7, ch = tid & 127;
        float gpart = 0.f;
        if (half == 0) {
            gpart = p.gt_b[ch];
            for (int k = 0; k < D_; k++) gpart += ns[t][k] * p.gt_w[k * D_ + ch];
        } else {
            for (int k = 0; k < D_; k++) gpart += nil[k] * p.gt_w[(D_ + k) * D_ + ch];
        }
        gzp[half][ch] = gpart;
    }
    __syncthreads();
    float upd = 0.f;
    if (tid < D_) {
        float g = sigm(gzp[0][tid] + gzp[1][tid]);
        upd     = g * niv + (1.f - g) * ns[t][tid];
    }
    {   // final LN + store
        float s = wsum64(tid < D_ ? upd : 0.f);
        if (lane == 0) red[wave] = s;
        __syncthreads();
        float mean = (red[0] + red[1]) * (1.f / 128.f);
        __syncthreads();
        float d  = upd - mean;
        float s2 = wsum64(tid < D_ ? d * d : 0.f);
        if (lane == 0) red[wave] = s2;
        __syncthreads();
        float var = (red[0] + red[1]) * (1.f / 128.f);
        if (tid < D_) {
            float o = d * rsqrtf(var + 1e-5f) * p.nn_ln_g[tid] + p.nn_ln_b[tid];
            p.out[((size_t)bs * N_ + t) * D_ + tid] = o;
        }
    }
}

extern "C" void kernel_launch(void* const* d_in, const int* in_sizes, int n_in,
                              void* d_out, int out_size, void* d_ws, size_t ws_size,
                              hipStream_t stream) {
    Params p;
    p.node_states   = (const float*)d_in[0];
    p.edge_features = (const float*)d_in[1];
    p.ee_w1   = (const float*)d_in[2];
    p.ee_b1   = (const float*)d_in[3];
    p.ee_ln_g = (const float*)d_in[4];
    p.ee_ln_b = (const float*)d_in[5];
    p.ee_w2   = (const float*)d_in[6];
    p.ee_b2   = (const float*)d_in[7];
    p.ts_w1   = (const float*)d_in[8];
    p.ts_b1   = (const float*)d_in[9];
    p.ts_ln_g = (const float*)d_in[10];
    p.ts_ln_b = (const float*)d_in[11];
    p.ts_w2   = (const float*)d_in[12];
    p.ts_b2   = (const float*)d_in[13];
    p.ts_w3   = (const float*)d_in[14];
    p.ts_b3   = (const float*)d_in[15];
    p.mc_w1   = (const float*)d_in[16];
    p.mc_b1   = (const float*)d_in[17];
    p.mc_ln_g = (const float*)d_in[18];
    p.mc_ln_b = (const float*)d_in[19];
    p.mc_w2   = (const float*)d_in[20];
    p.mc_b2   = (const float*)d_in[21];
    p.at_in_w  = (const float*)d_in[22];
    p.at_in_b  = (const float*)d_in[23];
    p.at_out_w = (const float*)d_in[24];
    p.at_out_b = (const float*)d_in[25];
    p.ag_w1   = (const float*)d_in[26];
    p.ag_b1   = (const float*)d_in[27];
    p.ag_ln_g = (const float*)d_in[28];
    p.ag_ln_b = (const float*)d_in[29];
    p.ag_w2   = (const float*)d_in[30];
    p.ag_b2   = (const float*)d_in[31];
    p.gt_w    = (const float*)d_in[32];
    p.gt_b    = (const float*)d_in[33];
    p.nn_ln_g = (const float*)d_in[34];
    p.nn_ln_b = (const float*)d_in[35];
    p.mn_ln_g = (const float*)d_in[36];
    p.mn_ln_b = (const float*)d_in[37];
    p.out     = (float*)d_out;

    hipLaunchKernelGGL(petri_kernel, dim3(B_ * S_ * N_), dim3(256), 0, stream, p);
}

// Round 6
// 1116.043 us; speedup vs baseline: 1.0694x; 1.0694x over previous
//
#include <hip/hip_runtime.h>

#define B_  16
#define S_  128
#define N_  13
#define D_  128
#define E_  6
#define M_  64
#define H_  4
#define HD_ 16

// row paddings (floats) to break 4-row same-bank LDS conflicts (stride %32 != 0,
// kept multiple of 4 floats so float4 loads stay 16B-aligned)
#define DP  (D_ + 4)       // ns rows:  132 % 32 = 4
#define MP  (M_ + 4)       // xbuf rows: 68 % 32 = 4
#define QP  (3 * M_ + 4)   // qkv rows: 196 % 32 = 4
#define EP  12             // encb rows: 12 -> j-stride 4 rows = 48 % 32 = 16

// compiler-only ordering for same-wave LDS park->read (DS pipe is in-order per wave;
// cross-wave reads here are dummy row-0 values whose results are discarded)
#define LDS_ORDER() __asm__ __volatile__("" ::: "memory")

// A&S 7.1.26 erf approximation, |eps| < 1.5e-7 (well under tolerance budget)
__device__ __forceinline__ float erf_fast(float x) {
    float ax = fabsf(x);
    float t  = __builtin_amdgcn_rcpf(fmaf(0.3275911f, ax, 1.0f));
    float p  = t * fmaf(t, fmaf(t, fmaf(t, fmaf(t, 1.061405429f, -1.453152027f),
                                        1.421413741f), -0.284496736f), 0.254829592f);
    float r  = fmaf(-p, __expf(-ax * ax), 1.0f);
    return copysignf(r, x);
}
__device__ __forceinline__ float geluf(float x) {
    return 0.5f * x * (1.0f + erf_fast(x * 0.7071067811865475f));
}
__device__ __forceinline__ float sigm(float x) { return 1.0f / (1.0f + __expf(-x)); }
__device__ __forceinline__ float wsum64(float v) {
#pragma unroll
    for (int o = 32; o; o >>= 1) v += __shfl_xor(v, o, 64);
    return v;
}
// 4 independent wave reductions, scalar refs (NO arrays -> stays in VGPRs)
__device__ __forceinline__ void wsum4s(float &a, float &b, float &c, float &d) {
#pragma unroll
    for (int o = 32; o; o >>= 1) {
        float ta = __shfl_xor(a, o, 64);
        float tb = __shfl_xor(b, o, 64);
        float tc = __shfl_xor(c, o, 64);
        float td = __shfl_xor(d, o, 64);
        a += ta; b += tb; c += tc; d += td;
    }
}
template <bool DOGELU>
__device__ __forceinline__ void ln4s(float &a, float &b, float &c, float &d,
                                     float lg, float lb) {
    float ma = a, mb = b, mc = c, md = d;
    wsum4s(ma, mb, mc, md);
    float da = a - ma * (1.f / 64.f);
    float db = b - mb * (1.f / 64.f);
    float dc = c - mc * (1.f / 64.f);
    float dd = d - md * (1.f / 64.f);
    float sa = da * da, sb = db * db, sc2 = dc * dc, sd = dd * dd;
    wsum4s(sa, sb, sc2, sd);
    a = da * rsqrtf(sa * (1.f / 64.f) + 1e-5f) * lg + lb;
    b = db * rsqrtf(sb * (1.f / 64.f) + 1e-5f) * lg + lb;
    c = dc * rsqrtf(sc2 * (1.f / 64.f) + 1e-5f) * lg + lb;
    d = dd * rsqrtf(sd * (1.f / 64.f) + 1e-5f) * lg + lb;
    if (DOGELU) { a = geluf(a); b = geluf(b); c = geluf(c); d = geluf(d); }
}

struct Params {
    const float *node_states, *edge_features;
    const float *ee_w1, *ee_b1, *ee_ln_g, *ee_ln_b, *ee_w2, *ee_b2;
    const float *ts_w1, *ts_b1, *ts_ln_g, *ts_ln_b, *ts_w2, *ts_b2, *ts_w3, *ts_b3;
    const float *mc_w1, *mc_b1, *mc_ln_g, *mc_ln_b, *mc_w2, *mc_b2;
    const float *at_in_w, *at_in_b, *at_out_w, *at_out_b;
    const float *ag_w1, *ag_b1, *ag_ln_g, *ag_ln_b, *ag_w2, *ag_b2;
    const float *gt_w, *gt_b, *nn_ln_g, *nn_ln_b, *mn_ln_g, *mn_ln_b;
    float *out;
};

// 4-edge-per-wave GEMV step: x0..x3 are float4 chunks (one per edge),
// w0..w3 the 4 weight rows for this lane's output channel.
#define DOT4X4(A0, A1, A2, A3)                              \
    A0 += x0.x * w0 + x0.y * w1 + x0.z * w2 + x0.w * w3;    \
    A1 += x1.x * w0 + x1.y * w1 + x1.z * w2 + x1.w * w3;    \
    A2 += x2.x * w0 + x2.y * w1 + x2.z * w2 + x2.w * w3;    \
    A3 += x3.x * w0 + x3.y * w1 + x3.z * w2 + x3.w * w3;

// one block per (b,s,target). 4 waves; wave w owns edges {w, w+4, w+8, (w==0: 12)},
// batched 4-wide inside each GEMV stage; inter-stage vectors parked in LDS.
// lane = M-channel. launch_bounds(256,4): VGPR cap 128, natural ~64, NO spill
// (min-waves=6 triggered pathological spill-to-40 + 413MB scratch — R5).
__global__ __launch_bounds__(256, 4) void petri_kernel(Params p) {
    const int tid  = threadIdx.x;
    const int wave = tid >> 6;
    const int lane = tid & 63;
    const int blk  = blockIdx.x;       // 0 .. B*S*N-1
    const int bs   = blk / N_;         // b*S + s
    const int t    = blk - bs * N_;    // target node

    const int  j0 = wave, j1 = wave + 4, j2 = wave + 8;
    const bool act3 = (wave == 0);
    const int  j3 = act3 ? 12 : 0;     // inactive -> alias row 0, results discarded

    __shared__ float ns[N_][DP];        // node states of this (b,s)
    __shared__ float xbuf[N_][MP];      // per-edge parking: t1 -> mh -> wm
    __shared__ float encb[N_][EP];      // encoded edge features (6 used)
    __shared__ float qkv[N_][QP];       // per source edge
    __shared__ float sc[H_][N_][N_];    // scores / attn
    __shared__ float wsm[H_][16];       // per-head column sums of attn
    __shared__ float aggp[M_];
    __shared__ float agg2[M_];
    __shared__ float a1l[D_];
    __shared__ float nil[D_];
    __shared__ float gzp[2][D_];
    __shared__ float red[4];

    // ---- stage node states -> LDS (row-wise due to padding) ----
    {
        const float4 *g4 = (const float4 *)(p.node_states + (size_t)bs * N_ * D_);
        for (int i = tid; i < N_ * (D_ / 4); i += 256) {
            int row = i >> 5, c4 = i & 31;           // D_/4 == 32
            ((float4 *)&ns[row][0])[c4] = g4[i];
        }
    }
    __syncthreads();

    // =======================  edge phase  =======================
    float acc0, acc1, acc2, acc3;

    // ---- E1: edge features @ ee_w1 -> LN -> gelu ----
    {
        const float *efb = p.edge_features + ((size_t)bs * N_ * N_ + t) * E_;
        const float *e0p = efb + j0 * (N_ * E_);
        const float *e1p = efb + j1 * (N_ * E_);
        const float *e2p = efb + j2 * (N_ * E_);
        const float *e3p = efb + j3 * (N_ * E_);
        float2 f0a = ((const float2 *)e0p)[0], f0b = ((const float2 *)e0p)[1], f0c = ((const float2 *)e0p)[2];
        float2 f1a = ((const float2 *)e1p)[0], f1b = ((const float2 *)e1p)[1], f1c = ((const float2 *)e1p)[2];
        float2 f2a = ((const float2 *)e2p)[0], f2b = ((const float2 *)e2p)[1], f2c = ((const float2 *)e2p)[2];
        float2 f3a = ((const float2 *)e3p)[0], f3b = ((const float2 *)e3p)[1], f3c = ((const float2 *)e3p)[2];
        float bb = p.ee_b1[lane];
        acc0 = acc1 = acc2 = acc3 = bb;
        { float w = p.ee_w1[0 * M_ + lane]; acc0 += f0a.x * w; acc1 += f1a.x * w; acc2 += f2a.x * w; acc3 += f3a.x * w; }
        { float w = p.ee_w1[1 * M_ + lane]; acc0 += f0a.y * w; acc1 += f1a.y * w; acc2 += f2a.y * w; acc3 += f3a.y * w; }
        { float w = p.ee_w1[2 * M_ + lane]; acc0 += f0b.x * w; acc1 += f1b.x * w; acc2 += f2b.x * w; acc3 += f3b.x * w; }
        { float w = p.ee_w1[3 * M_ + lane]; acc0 += f0b.y * w; acc1 += f1b.y * w; acc2 += f2b.y * w; acc3 += f3b.y * w; }
        { float w = p.ee_w1[4 * M_ + lane]; acc0 += f0c.x * w; acc1 += f1c.x * w; acc2 += f2c.x * w; acc3 += f3c.x * w; }
        { float w = p.ee_w1[5 * M_ + lane]; acc0 += f0c.y * w; acc1 += f1c.y * w; acc2 += f2c.y * w; acc3 += f3c.y * w; }
    }
    ln4s<true>(acc0, acc1, acc2, acc3, p.ee_ln_g[lane], p.ee_ln_b[lane]);

    // ---- E2: project back to E, park in encb ----
#pragma unroll
    for (int e = 0; e < E_; e++) {
        float w = p.ee_w2[lane * E_ + e];
        float r0 = acc0 * w, r1 = acc1 * w, r2 = acc2 * w, r3 = acc3 * w;
        wsum4s(r0, r1, r2, r3);
        if (lane == e) {
            float be = p.ee_b2[e];
            encb[j0][e] = r0 + be;
            encb[j1][e] = r1 + be;
            encb[j2][e] = r2 + be;
            if (act3) encb[j3][e] = r3 + be;
        }
    }
    LDS_ORDER();

    // broadcast-load enc vectors (per-edge) into registers
    float4 enA0 = *(const float4 *)&encb[j0][0]; float2 enB0 = *(const float2 *)&encb[j0][4];
    float4 enA1 = *(const float4 *)&encb[j1][0]; float2 enB1 = *(const float2 *)&encb[j1][4];
    float4 enA2 = *(const float4 *)&encb[j2][0]; float2 enB2 = *(const float2 *)&encb[j2][4];
    float4 enA3 = *(const float4 *)&encb[j3][0]; float2 enB3 = *(const float2 *)&encb[j3][4];

    // ---- TS: transition strength E -> M -> 32 -> 1 ----
    float ts0, ts1, ts2, ts3;
    {
        float t10, t11, t12, t13;
        float bb = p.ts_b1[lane];
        t10 = t11 = t12 = t13 = bb;
        { float w = p.ts_w1[0 * M_ + lane]; t10 += enA0.x * w; t11 += enA1.x * w; t12 += enA2.x * w; t13 += enA3.x * w; }
        { float w = p.ts_w1[1 * M_ + lane]; t10 += enA0.y * w; t11 += enA1.y * w; t12 += enA2.y * w; t13 += enA3.y * w; }
        { float w = p.ts_w1[2 * M_ + lane]; t10 += enA0.z * w; t11 += enA1.z * w; t12 += enA2.z * w; t13 += enA3.z * w; }
        { float w = p.ts_w1[3 * M_ + lane]; t10 += enA0.w * w; t11 += enA1.w * w; t12 += enA2.w * w; t13 += enA3.w * w; }
        { float w = p.ts_w1[4 * M_ + lane]; t10 += enB0.x * w; t11 += enB1.x * w; t12 += enB2.x * w; t13 += enB3.x * w; }
        { float w = p.ts_w1[5 * M_ + lane]; t10 += enB0.y * w; t11 += enB1.y * w; t12 += enB2.y * w; t13 += enB3.y * w; }
        ln4s<true>(t10, t11, t12, t13, p.ts_ln_g[lane], p.ts_ln_b[lane]);
        xbuf[j0][lane] = t10;
        xbuf[j1][lane] = t11;
        xbuf[j2][lane] = t12;
        if (act3) xbuf[j3][lane] = t13;
        LDS_ORDER();

        const int l31 = lane & 31;
        float b2v = p.ts_b2[l31];
        float t20 = b2v, t21 = b2v, t22 = b2v, t23 = b2v;
#pragma unroll 4
        for (int m4 = 0; m4 < M_ / 4; m4++) {
            float4 x0 = *(const float4 *)&xbuf[j0][4 * m4];
            float4 x1 = *(const float4 *)&xbuf[j1][4 * m4];
            float4 x2 = *(const float4 *)&xbuf[j2][4 * m4];
            float4 x3 = *(const float4 *)&xbuf[j3][4 * m4];
            const float *wr = p.ts_w2 + (4 * m4) * 32 + l31;
            float w0 = wr[0], w1 = wr[32], w2 = wr[64], w3 = wr[96];
            DOT4X4(t20, t21, t22, t23)
        }
        float w3v = p.ts_w3[l31], b3v = p.ts_b3[0];
        float r0 = geluf(t20) * w3v, r1 = geluf(t21) * w3v;
        float r2 = geluf(t22) * w3v, r3 = geluf(t23) * w3v;
        wsum4s(r0, r1, r2, r3);  // 32-halves duplicated -> x0.5
        ts0 = sigm(r0 * 0.5f + b3v);
        ts1 = sigm(r1 * 0.5f + b3v);
        ts2 = sigm(r2 * 0.5f + b3v);
        ts3 = sigm(r3 * 0.5f + b3v);
    }

    // ---- MC1: concat(src_state, enc) @ mc_w1 -> LN -> gelu, park mh ----
    {
        float bb = p.mc_b1[lane];
        acc0 = acc1 = acc2 = acc3 = bb;
#pragma unroll 4
        for (int d4 = 0; d4 < D_ / 4; d4++) {
            float4 x0 = *(const float4 *)&ns[j0][4 * d4];
            float4 x1 = *(const float4 *)&ns[j1][4 * d4];
            float4 x2 = *(const float4 *)&ns[j2][4 * d4];
            float4 x3 = *(const float4 *)&ns[j3][4 * d4];
            const float *wr = p.mc_w1 + (size_t)(4 * d4) * M_ + lane;
            float w0 = wr[0], w1 = wr[M_], w2 = wr[2 * M_], w3 = wr[3 * M_];
            DOT4X4(acc0, acc1, acc2, acc3)
        }
        { float w = p.mc_w1[(D_ + 0) * M_ + lane]; acc0 += enA0.x * w; acc1 += enA1.x * w; acc2 += enA2.x * w; acc3 += enA3.x * w; }
        { float w = p.mc_w1[(D_ + 1) * M_ + lane]; acc0 += enA0.y * w; acc1 += enA1.y * w; acc2 += enA2.y * w; acc3 += enA3.y * w; }
        { float w = p.mc_w1[(D_ + 2) * M_ + lane]; acc0 += enA0.z * w; acc1 += enA1.z * w; acc2 += enA2.z * w; acc3 += enA3.z * w; }
        { float w = p.mc_w1[(D_ + 3) * M_ + lane]; acc0 += enA0.w * w; acc1 += enA1.w * w; acc2 += enA2.w * w; acc3 += enA3.w * w; }
        { float w = p.mc_w1[(D_ + 4) * M_ + lane]; acc0 += enB0.x * w; acc1 += enB1.x * w; acc2 += enB2.x * w; acc3 += enB3.x * w; }
        { float w = p.mc_w1[(D_ + 5) * M_ + lane]; acc0 += enB0.y * w; acc1 += enB1.y * w; acc2 += enB2.y * w; acc3 += enB3.y * w; }
        ln4s<true>(acc0, acc1, acc2, acc3, p.mc_ln_g[lane], p.mc_ln_b[lane]);
        xbuf[j0][lane] = acc0;
        xbuf[j1][lane] = acc1;
        xbuf[j2][lane] = acc2;
        if (act3) xbuf[j3][lane] = acc3;   // mh (t1 consumed)
        LDS_ORDER();
    }

    // ---- MC2: mh @ mc_w2 ; wm = LN(msg*ts), park wm ----
    {
        float bb = p.mc_b2[lane];
        float m0 = bb, m1 = bb, m2 = bb, m3 = bb;
#pragma unroll 4
        for (int k4 = 0; k4 < M_ / 4; k4++) {
            float4 x0 = *(const float4 *)&xbuf[j0][4 * k4];
            float4 x1 = *(const float4 *)&xbuf[j1][4 * k4];
            float4 x2 = *(const float4 *)&xbuf[j2][4 * k4];
            float4 x3 = *(const float4 *)&xbuf[j3][4 * k4];
            const float *wr = p.mc_w2 + (size_t)(4 * k4) * M_ + lane;
            float w0 = wr[0], w1 = wr[M_], w2 = wr[2 * M_], w3 = wr[3 * M_];
            DOT4X4(m0, m1, m2, m3)
        }
        m0 *= ts0; m1 *= ts1; m2 *= ts2; m3 *= ts3;
        ln4s<false>(m0, m1, m2, m3, p.mn_ln_g[lane], p.mn_ln_b[lane]);
        xbuf[j0][lane] = m0;
        xbuf[j1][lane] = m1;
        xbuf[j2][lane] = m2;
        if (act3) xbuf[j3][lane] = m3;     // wm (mh consumed)
        LDS_ORDER();
    }

    // ---- AT: qkv = wm @ at_in_w + b ----
    {
        float qb = p.at_in_b[lane];
        float kb = p.at_in_b[M_ + lane];
        float vb = p.at_in_b[2 * M_ + lane];
        float qa0 = qb, qa1 = qb, qa2 = qb, qa3 = qb;
        float ka0 = kb, ka1 = kb, ka2 = kb, ka3 = kb;
        float va0 = vb, va1 = vb, va2 = vb, va3 = vb;
#define AT_STEP(COMP, WR)                                                  \
        { float wq = (WR)[lane], wk = (WR)[M_ + lane], wv = (WR)[2 * M_ + lane]; \
          qa0 += x0.COMP * wq; ka0 += x0.COMP * wk; va0 += x0.COMP * wv;   \
          qa1 += x1.COMP * wq; ka1 += x1.COMP * wk; va1 += x1.COMP * wv;   \
          qa2 += x2.COMP * wq; ka2 += x2.COMP * wk; va2 += x2.COMP * wv;   \
          qa3 += x3.COMP * wq; ka3 += x3.COMP * wk; va3 += x3.COMP * wv; }
#pragma unroll 2
        for (int k4 = 0; k4 < M_ / 4; k4++) {
            float4 x0 = *(const float4 *)&xbuf[j0][4 * k4];
            float4 x1 = *(const float4 *)&xbuf[j1][4 * k4];
            float4 x2 = *(const float4 *)&xbuf[j2][4 * k4];
            float4 x3 = *(const float4 *)&xbuf[j3][4 * k4];
            const float *wr = p.at_in_w + (size_t)(4 * k4) * 3 * M_;
            AT_STEP(x, wr)
            AT_STEP(y, wr + 3 * M_)
            AT_STEP(z, wr + 6 * M_)
            AT_STEP(w, wr + 9 * M_)
        }
#undef AT_STEP
        qkv[j0][lane] = qa0; qkv[j0][M_ + lane] = ka0; qkv[j0][2 * M_ + lane] = va0;
        qkv[j1][lane] = qa1; qkv[j1][M_ + lane] = ka1; qkv[j1][2 * M_ + lane] = va1;
        qkv[j2][lane] = qa2; qkv[j2][M_ + lane] = ka2; qkv[j2][2 * M_ + lane] = va2;
        if (act3) {
            qkv[j3][lane] = qa3; qkv[j3][M_ + lane] = ka3; qkv[j3][2 * M_ + lane] = va3;
        }
    }
    __syncthreads();

    // =======================  attention phase  =======================
    for (int pidx = tid; pidx < H_ * N_ * N_; pidx += 256) {
        int hh = pidx / (N_ * N_), r = pidx % (N_ * N_);
        int q = r / N_, k = r % N_;
        float s = 0.f;
#pragma unroll
        for (int d = 0; d < HD_; d++)
            s += qkv[q][hh * HD_ + d] * qkv[k][M_ + hh * HD_ + d];
        sc[hh][q][k] = s * 0.25f;  // 1/sqrt(16)
    }
    __syncthreads();
    if (tid < H_ * N_) {  // softmax rows
        int hh = tid / N_, q = tid % N_;
        float mx = -1e30f;
        for (int k = 0; k < N_; k++) mx = fmaxf(mx, sc[hh][q][k]);
        float se = 0.f;
        for (int k = 0; k < N_; k++) {
            float e = __expf(sc[hh][q][k] - mx);
            se += e; sc[hh][q][k] = e;
        }
        float inv = 1.f / se;
        for (int k = 0; k < N_; k++) sc[hh][q][k] *= inv;
    }
    __syncthreads();
    if (tid < H_ * N_) {  // column sums over q (mean-over-q is linear)
        int hh = tid / N_, k = tid % N_;
        float s = 0.f;
        for (int q = 0; q < N_; q++) s += sc[hh][q][k];
        wsm[hh][k] = s;
    }
    __syncthreads();
    if (tid < M_) {  // agg_pre = (1/13) * (colsum @ v)
        int hh  = tid >> 4;
        float s = 0.f;
        for (int k = 0; k < N_; k++) s += wsm[hh][k] * qkv[k][2 * M_ + tid];
        aggp[tid] = s * (1.0f / 13.0f);
    }
    __syncthreads();
    if (tid < M_) {  // at_out (after mean, by linearity)
        float s = p.at_out_b[tid];
        for (int k = 0; k < M_; k++) s += aggp[k] * p.at_out_w[k * M_ + tid];
        agg2[tid] = s;
    }
    __syncthreads();

    // =======================  node update phase  =======================
    float a1 = 0.f;
    if (tid < D_) {
        a1 = p.ag_b1[tid];
        for (int k = 0; k < M_; k++) a1 += agg2[k] * p.ag_w1[k * D_ + tid];
    }
    {   // LN over 128 (threads 0..127 = waves 0,1)
        float s = wsum64(tid < D_ ? a1 : 0.f);
        if (lane == 0) red[wave] = s;
        __syncthreads();
        float mean = (red[0] + red[1]) * (1.f / 128.f);
        __syncthreads();
        float d  = a1 - mean;
        float s2 = wsum64(tid < D_ ? d * d : 0.f);
        if (lane == 0) red[wave] = s2;
        __syncthreads();
        float var = (red[0] + red[1]) * (1.f / 128.f);
        __syncthreads();
        if (tid < D_)
            a1 = geluf(d * rsqrtf(var + 1e-5f) * p.ag_ln_g[tid] + p.ag_ln_b[tid]);
    }
    if (tid < D_) a1l[tid] = a1;
    __syncthreads();
    float niv = 0.f;
    if (tid < D_) {
        niv = p.ag_b2[tid];
        for (int k = 0; k < D_; k++) niv += a1l[k] * p.ag_w2[k * D_ + tid];
        nil[tid] = niv;
    }
    __syncthreads();
    {   // gate GEMV split across all 4 waves: half 0 -> node part, half 1 -> ni part
        int half = tid >> 7, ch = tid & 127;
        float gpart = 0.f;
        if (half == 0) {
            gpart = p.gt_b[ch];
            for (int k = 0; k < D_; k++) gpart += ns[t][k] * p.gt_w[k * D_ + ch];
        } else {
            for (int k = 0; k < D_; k++) gpart += nil[k] * p.gt_w[(D_ + k) * D_ + ch];
        }
        gzp[half][ch] = gpart;
    }
    __syncthreads();
    float upd = 0.f;
    if (tid < D_) {
        float g = sigm(gzp[0][tid] + gzp[1][tid]);
        upd     = g * niv + (1.f - g) * ns[t][tid];
    }
    {   // final LN + store
        float s = wsum64(tid < D_ ? upd : 0.f);
        if (lane == 0) red[wave] = s;
        __syncthreads();
        float mean = (red[0] + red[1]) * (1.f / 128.f);
        __syncthreads();
        float d  = upd - mean;
        float s2 = wsum64(tid < D_ ? d * d : 0.f);
        if (lane == 0) red[wave] = s2;
        __syncthreads();
        float var = (red[0] + red[1]) * (1.f / 128.f);
        if (tid < D_) {
            float o = d * rsqrtf(var + 1e-5f) * p.nn_ln_g[tid] + p.nn_ln_b[tid];
            p.out[((size_t)bs * N_ + t) * D_ + tid] = o;
        }
    }
}

extern "C" void kernel_launch(void* const* d_in, const int* in_sizes, int n_in,
                              void* d_out, int out_size, void* d_ws, size_t ws_size,
                              hipStream_t stream) {
    Params p;
    p.node_states   = (const float*)d_in[0];
    p.edge_features = (const float*)d_in[1];
    p.ee_w1   = (const float*)d_in[2];
    p.ee_b1   = (const float*)d_in[3];
    p.ee_ln_g = (const float*)d_in[4];
    p.ee_ln_b = (const float*)d_in[5];
    p.ee_w2   = (const float*)d_in[6];
    p.ee_b2   = (const float*)d_in[7];
    p.ts_w1   = (const float*)d_in[8];
    p.ts_b1   = (const float*)d_in[9];
    p.ts_ln_g = (const float*)d_in[10];
    p.ts_ln_b = (const float*)d_in[11];
    p.ts_w2   = (const float*)d_in[12];
    p.ts_b2   = (const float*)d_in[13];
    p.ts_w3   = (const float*)d_in[14];
    p.ts_b3   = (const float*)d_in[15];
    p.mc_w1   = (const float*)d_in[16];
    p.mc_b1   = (const float*)d_in[17];
    p.mc_ln_g = (const float*)d_in[18];
    p.mc_ln_b = (const float*)d_in[19];
    p.mc_w2   = (const float*)d_in[20];
    p.mc_b2   = (const float*)d_in[21];
    p.at_in_w  = (const float*)d_in[22];
    p.at_in_b  = (const float*)d_in[23];
    p.at_out_w = (const float*)d_in[24];
    p.at_out_b = (const float*)d_in[25];
    p.ag_w1   = (const float*)d_in[26];
    p.ag_b1   = (const float*)d_in[27];
    p.ag_ln_g = (const float*)d_in[28];
    p.ag_ln_b = (const float*)d_in[29];
    p.ag_w2   = (const float*)d_in[30];
    p.ag_b2   = (const float*)d_in[31];
    p.gt_w    = (const float*)d_in[32];
    p.gt_b    = (const float*)d_in[33];
    p.nn_ln_g = (const float*)d_in[34];
    p.nn_ln_b = (const float*)d_in[35];
    p.mn_ln_g = (const float*)d_in[36];
    p.mn_ln_b = (const float*)d_in[37];
    p.out     = (float*)d_out;

    hipLaunchKernelGGL(petri_kernel, dim3(B_ * S_ * N_), dim3(256), 0, stream, p);
}

// Round 7
// 1046.652 us; speedup vs baseline: 1.1403x; 1.0663x over previous
//
#include <hip/hip_runtime.h>

#define B_  16
#define S_  128
#define N_  13
#define D_  128
#define E_  6
#define M_  64
#define H_  4
#define HD_ 16

// row paddings (floats) to break 4-row same-bank LDS conflicts (stride %32 != 0,
// kept multiple of 4 floats so float4 loads stay 16B-aligned)
#define DP  (D_ + 4)       // ns rows:  132 % 32 = 4
#define MP  (M_ + 4)       // xbuf rows: 68 % 32 = 4
#define QP  (3 * M_ + 4)   // qkv rows: 196 % 32 = 4
#define EP  12             // encb rows: 12

// compiler-only ordering for same-wave LDS park->read (DS pipe is in-order per wave)
#define LDS_ORDER() __asm__ __volatile__("" ::: "memory")

typedef float v2f __attribute__((ext_vector_type(2)));
typedef float v4f __attribute__((ext_vector_type(4)));

#if __has_builtin(__builtin_elementwise_fma)
#define PKFMA(A, B, C) __builtin_elementwise_fma((A), (B), (C))
#else
#define PKFMA(A, B, C) ((A) * (B) + (C))
#endif
#define LO2(X) __builtin_shufflevector((X), (X), 0, 1)
#define HI2(X) __builtin_shufflevector((X), (X), 2, 3)

__device__ __forceinline__ v2f mkpair(float a, float b) { v2f r; r.x = a; r.y = b; return r; }
__device__ __forceinline__ float hsum2(v2f v) { return v.x + v.y; }

// A&S 7.1.26 erf approximation, |eps| < 1.5e-7
__device__ __forceinline__ float erf_fast(float x) {
    float ax = fabsf(x);
    float t  = __builtin_amdgcn_rcpf(fmaf(0.3275911f, ax, 1.0f));
    float p  = t * fmaf(t, fmaf(t, fmaf(t, fmaf(t, 1.061405429f, -1.453152027f),
                                        1.421413741f), -0.284496736f), 0.254829592f);
    float r  = fmaf(-p, __expf(-ax * ax), 1.0f);
    return copysignf(r, x);
}
__device__ __forceinline__ float geluf(float x) {
    return 0.5f * x * (1.0f + erf_fast(x * 0.7071067811865475f));
}
__device__ __forceinline__ float sigm(float x) { return 1.0f / (1.0f + __expf(-x)); }
__device__ __forceinline__ float wsum64(float v) {
#pragma unroll
    for (int o = 32; o; o >>= 1) v += __shfl_xor(v, o, 64);
    return v;
}
__device__ __forceinline__ void wsum4s(float &a, float &b, float &c, float &d) {
#pragma unroll
    for (int o = 32; o; o >>= 1) {
        float ta = __shfl_xor(a, o, 64);
        float tb = __shfl_xor(b, o, 64);
        float tc = __shfl_xor(c, o, 64);
        float td = __shfl_xor(d, o, 64);
        a += ta; b += tb; c += tc; d += td;
    }
}
template <bool DOGELU>
__device__ __forceinline__ void ln4s(float &a, float &b, float &c, float &d,
                                     float lg, float lb) {
    float ma = a, mb = b, mc = c, md = d;
    wsum4s(ma, mb, mc, md);
    float da = a - ma * (1.f / 64.f);
    float db = b - mb * (1.f / 64.f);
    float dc = c - mc * (1.f / 64.f);
    float dd = d - md * (1.f / 64.f);
    float sa = da * da, sb = db * db, sc2 = dc * dc, sd = dd * dd;
    wsum4s(sa, sb, sc2, sd);
    a = da * rsqrtf(sa * (1.f / 64.f) + 1e-5f) * lg + lb;
    b = db * rsqrtf(sb * (1.f / 64.f) + 1e-5f) * lg + lb;
    c = dc * rsqrtf(sc2 * (1.f / 64.f) + 1e-5f) * lg + lb;
    d = dd * rsqrtf(sd * (1.f / 64.f) + 1e-5f) * lg + lb;
    if (DOGELU) { a = geluf(a); b = geluf(b); c = geluf(c); d = geluf(d); }
}

struct Params {
    const float *node_states, *edge_features;
    const float *ee_w1, *ee_b1, *ee_ln_g, *ee_ln_b, *ee_w2, *ee_b2;
    const float *ts_w1, *ts_b1, *ts_ln_g, *ts_ln_b, *ts_w2, *ts_b2, *ts_w3, *ts_b3;
    const float *mc_w1, *mc_b1, *mc_ln_g, *mc_ln_b, *mc_w2, *mc_b2;
    const float *at_in_w, *at_in_b, *at_out_w, *at_out_b;
    const float *ag_w1, *ag_b1, *ag_ln_g, *ag_ln_b, *ag_w2, *ag_b2;
    const float *gt_w, *gt_b, *nn_ln_g, *nn_ln_b, *mn_ln_g, *mn_ln_b;
    float *out;
};

// packed 4-edge GEMV step: x0..x3 are v4f chunks, w01/w23 packed weight pairs.
#define PKD4(P0, P1, P2, P3)                                   \
    P0 = PKFMA(LO2(x0), w01, PKFMA(HI2(x0), w23, P0));         \
    P1 = PKFMA(LO2(x1), w01, PKFMA(HI2(x1), w23, P1));         \
    P2 = PKFMA(LO2(x2), w01, PKFMA(HI2(x2), w23, P2));         \
    P3 = PKFMA(LO2(x3), w01, PKFMA(HI2(x3), w23, P3));

// one block per (b,s,target). 4 waves; wave w owns edges {w, w+4, w+8, (w==0: 12)},
// batched 4-wide per GEMV stage; inter-stage vectors parked in LDS; v_pk_fma_f32
// packing via v2f accumulators. launch_bounds(256,4): no spill (R5: min-waves=6
// triggered pathological spill).
__global__ __launch_bounds__(256, 4) void petri_kernel(Params p) {
    const int tid  = threadIdx.x;
    const int wave = tid >> 6;
    const int lane = tid & 63;
    const int blk  = blockIdx.x;       // 0 .. B*S*N-1
    const int bs   = blk / N_;         // b*S + s
    const int t    = blk - bs * N_;    // target node

    const int  j0 = wave, j1 = wave + 4, j2 = wave + 8;
    const bool act3 = (wave == 0);
    const int  j3 = act3 ? 12 : 0;     // inactive -> alias row 0, results discarded

    __shared__ float ns[N_][DP];
    __shared__ float xbuf[N_][MP];      // per-edge parking: t1 -> mh -> wm
    __shared__ float encb[N_][EP];
    __shared__ float qkv[N_][QP];
    __shared__ float sc[H_][N_][N_];
    __shared__ float wsm[H_][16];
    __shared__ float aggp[M_];
    __shared__ float agg2[M_];
    __shared__ float a1l[D_];
    __shared__ float nil[D_];
    __shared__ float gzp[2][D_];
    __shared__ float red[4];

    // ---- stage node states -> LDS (row-wise due to padding) ----
    {
        const v4f *g4 = (const v4f *)(p.node_states + (size_t)bs * N_ * D_);
        for (int i = tid; i < N_ * (D_ / 4); i += 256) {
            int row = i >> 5, c4 = i & 31;           // D_/4 == 32
            ((v4f *)&ns[row][0])[c4] = g4[i];
        }
    }
    __syncthreads();

    // =======================  edge phase  =======================
    float acc0, acc1, acc2, acc3;

    // ---- E1: edge features @ ee_w1 -> LN -> gelu (packed over k-pairs) ----
    {
        const float *efb = p.edge_features + ((size_t)bs * N_ * N_ + t) * E_;
        const v2f *e0p = (const v2f *)(efb + j0 * (N_ * E_));
        const v2f *e1p = (const v2f *)(efb + j1 * (N_ * E_));
        const v2f *e2p = (const v2f *)(efb + j2 * (N_ * E_));
        const v2f *e3p = (const v2f *)(efb + j3 * (N_ * E_));
        float bb = p.ee_b1[lane];
        v2f p0 = {bb, 0.f}, p1 = {bb, 0.f}, p2 = {bb, 0.f}, p3 = {bb, 0.f};
#pragma unroll
        for (int e2 = 0; e2 < 3; e2++) {
            v2f w01 = mkpair(p.ee_w1[(2 * e2) * M_ + lane], p.ee_w1[(2 * e2 + 1) * M_ + lane]);
            p0 = PKFMA(e0p[e2], w01, p0);
            p1 = PKFMA(e1p[e2], w01, p1);
            p2 = PKFMA(e2p[e2], w01, p2);
            p3 = PKFMA(e3p[e2], w01, p3);
        }
        acc0 = hsum2(p0); acc1 = hsum2(p1); acc2 = hsum2(p2); acc3 = hsum2(p3);
    }
    ln4s<true>(acc0, acc1, acc2, acc3, p.ee_ln_g[lane], p.ee_ln_b[lane]);

    // ---- E2: project back to E, park in encb ----
#pragma unroll
    for (int e = 0; e < E_; e++) {
        float w = p.ee_w2[lane * E_ + e];
        float r0 = acc0 * w, r1 = acc1 * w, r2 = acc2 * w, r3 = acc3 * w;
        wsum4s(r0, r1, r2, r3);
        if (lane == e) {
            float be = p.ee_b2[e];
            encb[j0][e] = r0 + be;
            encb[j1][e] = r1 + be;
            encb[j2][e] = r2 + be;
            if (act3) encb[j3][e] = r3 + be;
        }
    }
    LDS_ORDER();

    // broadcast-load enc vectors as 3 pairs per edge
    v2f en0a = ((const v2f *)&encb[j0][0])[0], en0b = ((const v2f *)&encb[j0][0])[1], en0c = ((const v2f *)&encb[j0][0])[2];
    v2f en1a = ((const v2f *)&encb[j1][0])[0], en1b = ((const v2f *)&encb[j1][0])[1], en1c = ((const v2f *)&encb[j1][0])[2];
    v2f en2a = ((const v2f *)&encb[j2][0])[0], en2b = ((const v2f *)&encb[j2][0])[1], en2c = ((const v2f *)&encb[j2][0])[2];
    v2f en3a = ((const v2f *)&encb[j3][0])[0], en3b = ((const v2f *)&encb[j3][0])[1], en3c = ((const v2f *)&encb[j3][0])[2];

    // ---- TS: transition strength E -> M -> 32 -> 1 ----
    float ts0, ts1, ts2, ts3;
    {
        float bb = p.ts_b1[lane];
        v2f p0 = {bb, 0.f}, p1 = {bb, 0.f}, p2 = {bb, 0.f}, p3 = {bb, 0.f};
        {
            v2f w = mkpair(p.ts_w1[0 * M_ + lane], p.ts_w1[1 * M_ + lane]);
            p0 = PKFMA(en0a, w, p0); p1 = PKFMA(en1a, w, p1);
            p2 = PKFMA(en2a, w, p2); p3 = PKFMA(en3a, w, p3);
        }
        {
            v2f w = mkpair(p.ts_w1[2 * M_ + lane], p.ts_w1[3 * M_ + lane]);
            p0 = PKFMA(en0b, w, p0); p1 = PKFMA(en1b, w, p1);
            p2 = PKFMA(en2b, w, p2); p3 = PKFMA(en3b, w, p3);
        }
        {
            v2f w = mkpair(p.ts_w1[4 * M_ + lane], p.ts_w1[5 * M_ + lane]);
            p0 = PKFMA(en0c, w, p0); p1 = PKFMA(en1c, w, p1);
            p2 = PKFMA(en2c, w, p2); p3 = PKFMA(en3c, w, p3);
        }
        float t10 = hsum2(p0), t11 = hsum2(p1), t12 = hsum2(p2), t13 = hsum2(p3);
        ln4s<true>(t10, t11, t12, t13, p.ts_ln_g[lane], p.ts_ln_b[lane]);
        xbuf[j0][lane] = t10;
        xbuf[j1][lane] = t11;
        xbuf[j2][lane] = t12;
        if (act3) xbuf[j3][lane] = t13;
        LDS_ORDER();

        const int l31 = lane & 31;
        float b2v = p.ts_b2[l31];
        v2f q0 = {b2v, 0.f}, q1 = {b2v, 0.f}, q2 = {b2v, 0.f}, q3 = {b2v, 0.f};
#pragma unroll 4
        for (int m4 = 0; m4 < M_ / 4; m4++) {
            v4f x0 = *(const v4f *)&xbuf[j0][4 * m4];
            v4f x1 = *(const v4f *)&xbuf[j1][4 * m4];
            v4f x2 = *(const v4f *)&xbuf[j2][4 * m4];
            v4f x3 = *(const v4f *)&xbuf[j3][4 * m4];
            const float *wr = p.ts_w2 + (4 * m4) * 32 + l31;
            v2f w01 = mkpair(wr[0], wr[32]);
            v2f w23 = mkpair(wr[64], wr[96]);
            PKD4(q0, q1, q2, q3)
        }
        float t20 = hsum2(q0), t21 = hsum2(q1), t22 = hsum2(q2), t23 = hsum2(q3);
        float w3v = p.ts_w3[l31], b3v = p.ts_b3[0];
        float r0 = geluf(t20) * w3v, r1 = geluf(t21) * w3v;
        float r2 = geluf(t22) * w3v, r3 = geluf(t23) * w3v;
        wsum4s(r0, r1, r2, r3);  // 32-halves duplicated -> x0.5
        ts0 = sigm(r0 * 0.5f + b3v);
        ts1 = sigm(r1 * 0.5f + b3v);
        ts2 = sigm(r2 * 0.5f + b3v);
        ts3 = sigm(r3 * 0.5f + b3v);
    }

    // ---- MC1: concat(src_state, enc) @ mc_w1 -> LN -> gelu, park mh ----
    {
        float bb = p.mc_b1[lane];
        v2f p0 = {bb, 0.f}, p1 = {bb, 0.f}, p2 = {bb, 0.f}, p3 = {bb, 0.f};
#pragma unroll 4
        for (int d4 = 0; d4 < D_ / 4; d4++) {
            v4f x0 = *(const v4f *)&ns[j0][4 * d4];
            v4f x1 = *(const v4f *)&ns[j1][4 * d4];
            v4f x2 = *(const v4f *)&ns[j2][4 * d4];
            v4f x3 = *(const v4f *)&ns[j3][4 * d4];
            const float *wr = p.mc_w1 + (size_t)(4 * d4) * M_ + lane;
            v2f w01 = mkpair(wr[0], wr[M_]);
            v2f w23 = mkpair(wr[2 * M_], wr[3 * M_]);
            PKD4(p0, p1, p2, p3)
        }
        {
            v2f w = mkpair(p.mc_w1[(D_ + 0) * M_ + lane], p.mc_w1[(D_ + 1) * M_ + lane]);
            p0 = PKFMA(en0a, w, p0); p1 = PKFMA(en1a, w, p1);
            p2 = PKFMA(en2a, w, p2); p3 = PKFMA(en3a, w, p3);
        }
        {
            v2f w = mkpair(p.mc_w1[(D_ + 2) * M_ + lane], p.mc_w1[(D_ + 3) * M_ + lane]);
            p0 = PKFMA(en0b, w, p0); p1 = PKFMA(en1b, w, p1);
            p2 = PKFMA(en2b, w, p2); p3 = PKFMA(en3b, w, p3);
        }
        {
            v2f w = mkpair(p.mc_w1[(D_ + 4) * M_ + lane], p.mc_w1[(D_ + 5) * M_ + lane]);
            p0 = PKFMA(en0c, w, p0); p1 = PKFMA(en1c, w, p1);
            p2 = PKFMA(en2c, w, p2); p3 = PKFMA(en3c, w, p3);
        }
        acc0 = hsum2(p0); acc1 = hsum2(p1); acc2 = hsum2(p2); acc3 = hsum2(p3);
        ln4s<true>(acc0, acc1, acc2, acc3, p.mc_ln_g[lane], p.mc_ln_b[lane]);
        xbuf[j0][lane] = acc0;
        xbuf[j1][lane] = acc1;
        xbuf[j2][lane] = acc2;
        if (act3) xbuf[j3][lane] = acc3;   // mh (t1 consumed)
        LDS_ORDER();
    }

    // ---- MC2: mh @ mc_w2 ; wm = LN(msg*ts), park wm ----
    {
        float bb = p.mc_b2[lane];
        v2f p0 = {bb, 0.f}, p1 = {bb, 0.f}, p2 = {bb, 0.f}, p3 = {bb, 0.f};
#pragma unroll 4
        for (int k4 = 0; k4 < M_ / 4; k4++) {
            v4f x0 = *(const v4f *)&xbuf[j0][4 * k4];
            v4f x1 = *(const v4f *)&xbuf[j1][4 * k4];
            v4f x2 = *(const v4f *)&xbuf[j2][4 * k4];
            v4f x3 = *(const v4f *)&xbuf[j3][4 * k4];
            const float *wr = p.mc_w2 + (size_t)(4 * k4) * M_ + lane;
            v2f w01 = mkpair(wr[0], wr[M_]);
            v2f w23 = mkpair(wr[2 * M_], wr[3 * M_]);
            PKD4(p0, p1, p2, p3)
        }
        float m0 = hsum2(p0), m1 = hsum2(p1), m2 = hsum2(p2), m3 = hsum2(p3);
        m0 *= ts0; m1 *= ts1; m2 *= ts2; m3 *= ts3;
        ln4s<false>(m0, m1, m2, m3, p.mn_ln_g[lane], p.mn_ln_b[lane]);
        xbuf[j0][lane] = m0;
        xbuf[j1][lane] = m1;
        xbuf[j2][lane] = m2;
        if (act3) xbuf[j3][lane] = m3;     // wm (mh consumed)
        LDS_ORDER();
    }

    // ---- AT: qkv = wm @ at_in_w + b ----
    {
        float qb = p.at_in_b[lane];
        float kb = p.at_in_b[M_ + lane];
        float vb = p.at_in_b[2 * M_ + lane];
        v2f qp0 = {qb, 0.f}, qp1 = {qb, 0.f}, qp2 = {qb, 0.f}, qp3 = {qb, 0.f};
        v2f kp0 = {kb, 0.f}, kp1 = {kb, 0.f}, kp2 = {kb, 0.f}, kp3 = {kb, 0.f};
        v2f vp0 = {vb, 0.f}, vp1 = {vb, 0.f}, vp2 = {vb, 0.f}, vp3 = {vb, 0.f};
#pragma unroll 2
        for (int k4 = 0; k4 < M_ / 4; k4++) {
            v4f x0 = *(const v4f *)&xbuf[j0][4 * k4];
            v4f x1 = *(const v4f *)&xbuf[j1][4 * k4];
            v4f x2 = *(const v4f *)&xbuf[j2][4 * k4];
            v4f x3 = *(const v4f *)&xbuf[j3][4 * k4];
            const float *wr = p.at_in_w + (size_t)(4 * k4) * 3 * M_;
            {
                v2f w01 = mkpair(wr[lane], wr[3 * M_ + lane]);
                v2f w23 = mkpair(wr[6 * M_ + lane], wr[9 * M_ + lane]);
                PKD4(qp0, qp1, qp2, qp3)
            }
            {
                v2f w01 = mkpair(wr[M_ + lane], wr[4 * M_ + lane]);
                v2f w23 = mkpair(wr[7 * M_ + lane], wr[10 * M_ + lane]);
                PKD4(kp0, kp1, kp2, kp3)
            }
            {
                v2f w01 = mkpair(wr[2 * M_ + lane], wr[5 * M_ + lane]);
                v2f w23 = mkpair(wr[8 * M_ + lane], wr[11 * M_ + lane]);
                PKD4(vp0, vp1, vp2, vp3)
            }
        }
        qkv[j0][lane] = hsum2(qp0); qkv[j0][M_ + lane] = hsum2(kp0); qkv[j0][2 * M_ + lane] = hsum2(vp0);
        qkv[j1][lane] = hsum2(qp1); qkv[j1][M_ + lane] = hsum2(kp1); qkv[j1][2 * M_ + lane] = hsum2(vp1);
        qkv[j2][lane] = hsum2(qp2); qkv[j2][M_ + lane] = hsum2(kp2); qkv[j2][2 * M_ + lane] = hsum2(vp2);
        if (act3) {
            qkv[j3][lane] = hsum2(qp3); qkv[j3][M_ + lane] = hsum2(kp3); qkv[j3][2 * M_ + lane] = hsum2(vp3);
        }
    }
    __syncthreads();

    // =======================  attention phase  =======================
    for (int pidx = tid; pidx < H_ * N_ * N_; pidx += 256) {
        int hh = pidx / (N_ * N_), r = pidx % (N_ * N_);
        int q = r / N_, k = r % N_;
        const v2f *qr = (const v2f *)&qkv[q][hh * HD_];
        const v2f *kr = (const v2f *)&qkv[k][M_ + hh * HD_];
        v2f sp = {0.f, 0.f};
#pragma unroll
        for (int d = 0; d < HD_ / 2; d++) sp = PKFMA(qr[d], kr[d], sp);
        sc[hh][q][k] = hsum2(sp) * 0.25f;  // 1/sqrt(16)
    }
    __syncthreads();
    if (tid < H_ * N_) {  // softmax rows
        int hh = tid / N_, q = tid % N_;
        float mx = -1e30f;
        for (int k = 0; k < N_; k++) mx = fmaxf(mx, sc[hh][q][k]);
        float se = 0.f;
        for (int k = 0; k < N_; k++) {
            float e = __expf(sc[hh][q][k] - mx);
            se += e; sc[hh][q][k] = e;
        }
        float inv = 1.f / se;
        for (int k = 0; k < N_; k++) sc[hh][q][k] *= inv;
    }
    __syncthreads();
    if (tid < H_ * N_) {  // column sums over q (mean-over-q is linear)
        int hh = tid / N_, k = tid % N_;
        float s = 0.f;
        for (int q = 0; q < N_; q++) s += sc[hh][q][k];
        wsm[hh][k] = s;
    }
    __syncthreads();
    if (tid < M_) {  // agg_pre = (1/13) * (colsum @ v)
        int hh  = tid >> 4;
        float s = 0.f;
        for (int k = 0; k < N_; k++) s += wsm[hh][k] * qkv[k][2 * M_ + tid];
        aggp[tid] = s * (1.0f / 13.0f);
    }
    __syncthreads();
    if (tid < M_) {  // at_out (after mean, by linearity)
        const v2f *a2 = (const v2f *)aggp;
        v2f sp = {p.at_out_b[tid], 0.f};
#pragma unroll 8
        for (int k2 = 0; k2 < M_ / 2; k2++) {
            v2f w = mkpair(p.at_out_w[(2 * k2) * M_ + tid], p.at_out_w[(2 * k2 + 1) * M_ + tid]);
            sp = PKFMA(a2[k2], w, sp);
        }
        agg2[tid] = hsum2(sp);
    }
    __syncthreads();

    // =======================  node update phase  =======================
    float a1 = 0.f;
    if (tid < D_) {
        const v2f *a2 = (const v2f *)agg2;
        v2f sp = {p.ag_b1[tid], 0.f};
#pragma unroll 8
        for (int k2 = 0; k2 < M_ / 2; k2++) {
            v2f w = mkpair(p.ag_w1[(2 * k2) * D_ + tid], p.ag_w1[(2 * k2 + 1) * D_ + tid]);
            sp = PKFMA(a2[k2], w, sp);
        }
        a1 = hsum2(sp);
    }
    {   // LN over 128 (threads 0..127 = waves 0,1)
        float s = wsum64(tid < D_ ? a1 : 0.f);
        if (lane == 0) red[wave] = s;
        __syncthreads();
        float mean = (red[0] + red[1]) * (1.f / 128.f);
        __syncthreads();
        float d  = a1 - mean;
        float s2 = wsum64(tid < D_ ? d * d : 0.f);
        if (lane == 0) red[wave] = s2;
        __syncthreads();
        float var = (red[0] + red[1]) * (1.f / 128.f);
        __syncthreads();
        if (tid < D_)
            a1 = geluf(d * rsqrtf(var + 1e-5f) * p.ag_ln_g[tid] + p.ag_ln_b[tid]);
    }
    if (tid < D_) a1l[tid] = a1;
    __syncthreads();
    float niv = 0.f;
    if (tid < D_) {
        const v2f *a2 = (const v2f *)a1l;
        v2f sp = {p.ag_b2[tid], 0.f};
#pragma unroll 8
        for (int k2 = 0; k2 < D_ / 2; k2++) {
            v2f w = mkpair(p.ag_w2[(2 * k2) * D_ + tid], p.ag_w2[(2 * k2 + 1) * D_ + tid]);
            sp = PKFMA(a2[k2], w, sp);
        }
        niv = hsum2(sp);
        nil[tid] = niv;
    }
    __syncthreads();
    {   // gate GEMV split across all 4 waves: half 0 -> node part, half 1 -> ni part
        int half = tid >> 7, ch = tid & 127;
        v2f sp = {0.f, 0.f};
        if (half == 0) {
            sp.x = p.gt_b[ch];
            const v2f *x2 = (const v2f *)&ns[t][0];
#pragma unroll 8
            for (int k2 = 0; k2 < D_ / 2; k2++) {
                v2f w = mkpair(p.gt_w[(2 * k2) * D_ + ch], p.gt_w[(2 * k2 + 1) * D_ + ch]);
                sp = PKFMA(x2[k2], w, sp);
            }
        } else {
            const v2f *x2 = (const v2f *)nil;
#pragma unroll 8
            for (int k2 = 0; k2 < D_ / 2; k2++) {
                v2f w = mkpair(p.gt_w[(D_ + 2 * k2) * D_ + ch], p.gt_w[(D_ + 2 * k2 + 1) * D_ + ch]);
                sp = PKFMA(x2[k2], w, sp);
            }
        }
        gzp[half][ch] = hsum2(sp);
    }
    __syncthreads();
    float upd = 0.f;
    if (tid < D_) {
        float g = sigm(gzp[0][tid] + gzp[1][tid]);
        upd     = g * niv + (1.f - g) * ns[t][tid];
    }
    {   // final LN + store
        float s = wsum64(tid < D_ ? upd : 0.f);
        if (lane == 0) red[wave] = s;
        __syncthreads();
        float mean = (red[0] + red[1]) * (1.f / 128.f);
        __syncthreads();
        float d  = upd - mean;
        float s2 = wsum64(tid < D_ ? d * d : 0.f);
        if (lane == 0) red[wave] = s2;
        __syncthreads();
        float var = (red[0] + red[1]) * (1.f / 128.f);
        if (tid < D_) {
            float o = d * rsqrtf(var + 1e-5f) * p.nn_ln_g[tid] + p.nn_ln_b[tid];
            p.out[((size_t)bs * N_ + t) * D_ + tid] = o;
        }
    }
}

extern "C" void kernel_launch(void* const* d_in, const int* in_sizes, int n_in,
                              void* d_out, int out_size, void* d_ws, size_t ws_size,
                              hipStream_t stream) {
    Params p;
    p.node_states   = (const float*)d_in[0];
    p.edge_features = (const float*)d_in[1];
    p.ee_w1   = (const float*)d_in[2];
    p.ee_b1   = (const float*)d_in[3];
    p.ee_ln_g = (const float*)d_in[4];
    p.ee_ln_b = (const float*)d_in[5];
    p.ee_w2   = (const float*)d_in[6];
    p.ee_b2   = (const float*)d_in[7];
    p.ts_w1   = (const float*)d_in[8];
    p.ts_b1   = (const float*)d_in[9];
    p.ts_ln_g = (const float*)d_in[10];
    p.ts_ln_b = (const float*)d_in[11];
    p.ts_w2   = (const float*)d_in[12];
    p.ts_b2   = (const float*)d_in[13];
    p.ts_w3   = (const float*)d_in[14];
    p.ts_b3   = (const float*)d_in[15];
    p.mc_w1   = (const float*)d_in[16];
    p.mc_b1   = (const float*)d_in[17];
    p.mc_ln_g = (const float*)d_in[18];
    p.mc_ln_b = (const float*)d_in[19];
    p.mc_w2   = (const float*)d_in[20];
    p.mc_b2   = (const float*)d_in[21];
    p.at_in_w  = (const float*)d_in[22];
    p.at_in_b  = (const float*)d_in[23];
    p.at_out_w = (const float*)d_in[24];
    p.at_out_b = (const float*)d_in[25];
    p.ag_w1   = (const float*)d_in[26];
    p.ag_b1   = (const float*)d_in[27];
    p.ag_ln_g = (const float*)d_in[28];
    p.ag_ln_b = (const float*)d_in[29];
    p.ag_w2   = (const float*)d_in[30];
    p.ag_b2   = (const float*)d_in[31];
    p.gt_w    = (const float*)d_in[32];
    p.gt_b    = (const float*)d_in[33];
    p.nn_ln_g = (const float*)d_in[34];
    p.nn_ln_b = (const float*)d_in[35];
    p.mn_ln_g = (const float*)d_in[36];
    p.mn_ln_b = (const float*)d_in[37];
    p.out     = (float*)d_out;

    hipLaunchKernelGGL(petri_kernel, dim3(B_ * S_ * N_), dim3(256), 0, stream, p);
}